// Round 3
// baseline (346.313 us; speedup 1.0000x reference)
//
#include <hip/hip_runtime.h>
#include <stdint.h>

// ---------------------------------------------------------------------------
// CTBG circuit, round 11.
//   r10 post-mortem: gemm_a32 99->70us (pipeline works), BUT accounting shows
//   ~240us hides in the mid-chain: combo1+combo2 (64x64-tile, 2-barrier BK=32,
//   4 MFMA/wave/iter) ~ 150-185us. That's the real bottleneck now.
//   r11: reassociate the weight algebra to eliminate the 1536^3 GEMM:
//     t1   = w1t (*) wibot_ui            [512,1536] K=1536   (2.4 GF)
//     w1ct = w1t (*) wi_topnt + t1 (*) we_nt   (fused, K=3072 virtual, 4.8 GF)
//     b1c  = b1 + w1t.gpi_b + t1.gpe_b   (bc eliminated)
//   Both combines use the r10 pipelined structure (BK=64, dbuf, 1 barrier).
//   prep: wi_bot flips to non-transposing prep -> wibot_ui[u][i].
//   gemm_a32 / gemm_bt / head byte-identical to r10.
// ---------------------------------------------------------------------------

typedef __attribute__((ext_vector_type(8))) short short8;
typedef __attribute__((ext_vector_type(4))) float floatx4;

typedef const __attribute__((address_space(1))) void* gas1_cvp;
typedef __attribute__((address_space(3))) void* gas3_vp;

__device__ __forceinline__ void load_lds16(const void* g, void* s) {
    __builtin_amdgcn_global_load_lds((gas1_cvp)g, (gas3_vp)s, 16, 0, 0);
}

__device__ __forceinline__ unsigned short f2bf(float f) {
    unsigned int u = __float_as_uint(f);
    u = u + 0x7fffu + ((u >> 16) & 1u);          // RNE
    return (unsigned short)(u >> 16);
}
__device__ __forceinline__ float bf2f(unsigned short h) {
    return __uint_as_float(((unsigned int)h) << 16);
}
__device__ __forceinline__ short8 cvt8(float4 a, float4 b) {
    short8 r;
    r[0] = (short)f2bf(a.x); r[1] = (short)f2bf(a.y);
    r[2] = (short)f2bf(a.z); r[3] = (short)f2bf(a.w);
    r[4] = (short)f2bf(b.x); r[5] = (short)f2bf(b.y);
    r[6] = (short)f2bf(b.z); r[7] = (short)f2bf(b.w);
    return r;
}

// ---------------------------------------------------------------------------
// Prep bodies. Block = 256 threads.
// Transposing: out[n][k] = bf16( w[k][n] * (mask ? mask[n][k] : 1) )
// ---------------------------------------------------------------------------
__device__ __forceinline__ void dev_prep_t(
        float (*tile)[65],
        const float* __restrict__ w, const float* __restrict__ mask,
        unsigned short* __restrict__ out,
        int ldw, int ldm, int ldo, int bx, int by) {
    int n0 = bx * 64;
    int k0 = by * 64;
    int t = threadIdx.x;
    int c4 = (t & 15) * 4;
    int r  = t >> 4;

    #pragma unroll
    for (int p = 0; p < 4; ++p) {
        int kk = r + p * 16;
        float4 v = *(const float4*)(w + (size_t)(k0 + kk) * ldw + n0 + c4);
        tile[c4 + 0][kk] = v.x;
        tile[c4 + 1][kk] = v.y;
        tile[c4 + 2][kk] = v.z;
        tile[c4 + 3][kk] = v.w;
    }
    __syncthreads();
    #pragma unroll
    for (int p = 0; p < 4; ++p) {
        int nn = r + p * 16;
        float mx = 1.f, my = 1.f, mz = 1.f, mw = 1.f;
        if (mask) {
            float4 m = *(const float4*)(mask + (size_t)(n0 + nn) * ldm + k0 + c4);
            mx = m.x; my = m.y; mz = m.z; mw = m.w;
        }
        ushort4 o;
        o.x = f2bf(tile[nn][c4 + 0] * mx);
        o.y = f2bf(tile[nn][c4 + 1] * my);
        o.z = f2bf(tile[nn][c4 + 2] * mz);
        o.w = f2bf(tile[nn][c4 + 3] * mw);
        *(ushort4*)(out + (size_t)(n0 + nn) * ldo + k0 + c4) = o;
    }
}

// Non-transposing: out[r][c] = bf16( w[r][c] * mask[c][r] )
__device__ __forceinline__ void dev_prep_nt(
        float (*tile)[65],
        const float* __restrict__ w, const float* __restrict__ mask,
        unsigned short* __restrict__ out,
        int ldw, int ldm, int ldo, int bx, int by) {
    int j0 = bx * 64;
    int i0 = by * 64;
    int t = threadIdx.x;
    int c4 = (t & 15) * 4;
    int r  = t >> 4;

    #pragma unroll
    for (int p = 0; p < 4; ++p) {
        int jj = r + p * 16;
        float4 m = *(const float4*)(mask + (size_t)(j0 + jj) * ldm + i0 + c4);
        tile[c4 + 0][jj] = m.x;
        tile[c4 + 1][jj] = m.y;
        tile[c4 + 2][jj] = m.z;
        tile[c4 + 3][jj] = m.w;
    }
    __syncthreads();
    #pragma unroll
    for (int p = 0; p < 4; ++p) {
        int ii = r + p * 16;
        float4 v = *(const float4*)(w + (size_t)(i0 + ii) * ldw + j0 + c4);
        ushort4 o;
        o.x = f2bf(v.x * tile[ii][c4 + 0]);
        o.y = f2bf(v.y * tile[ii][c4 + 1]);
        o.z = f2bf(v.z * tile[ii][c4 + 2]);
        o.w = f2bf(v.w * tile[ii][c4 + 3]);
        *(ushort4*)(out + (size_t)(i0 + ii) * ldo + j0 + c4) = o;
    }
}

// One kernel for all 5 weight preps, flattened 1D grid (1984 blocks).
// wi_topnt[j][i] = gpi_w_top[j][i]*gpi_mask[i][j]          (prep_nt)
// wibot_ui[u][i] = gpi_w_bot[u][i]*gpi_mask[i][1536+u]     (prep_nt)  <- r11
// we_nt[j][u]    = gpe_w[j][u]*gpe_mask[u][j]              (prep_nt)
// w1t[n][i]      = w1[i][n]                                 (prep_t)
// w2t[n][k]      = w2[k][n]                                 (prep_t)
__global__ __launch_bounds__(256) void prep_all_kernel(
        const float* __restrict__ gpe_w, const float* __restrict__ gpe_mask,
        const float* __restrict__ gpi_w, const float* __restrict__ gpi_mask,
        const float* __restrict__ w1, const float* __restrict__ w2,
        unsigned short* __restrict__ wi_topnt, unsigned short* __restrict__ wibot_ui,
        unsigned short* __restrict__ we_nt, unsigned short* __restrict__ w1t,
        unsigned short* __restrict__ w2t) {
    __shared__ float tile[64][65];
    int b = blockIdx.x;
    if (b < 576) {
        dev_prep_nt(tile, gpi_w, gpi_mask, wi_topnt, 1536, 3072, 1536,
                    b % 24, b / 24);
    } else if (b < 1152) {
        int lb = b - 576;
        dev_prep_nt(tile, gpi_w + (size_t)1536 * 1536, gpi_mask + 1536, wibot_ui,
                    1536, 3072, 1536, lb % 24, lb / 24);
    } else if (b < 1728) {
        int lb = b - 1152;
        dev_prep_nt(tile, gpe_w, gpe_mask, we_nt, 1536, 1536, 1536,
                    lb % 24, lb / 24);
    } else if (b < 1920) {
        int lb = b - 1728;
        dev_prep_t(tile, w1, nullptr, w1t, 512, 0, 1536, lb % 8, lb / 8);
    } else {
        int lb = b - 1920;
        dev_prep_t(tile, w2, nullptr, w2t, 512, 0, 512, lb % 8, lb / 8);
    }
}

// ---------------------------------------------------------------------------
// Pipelined 64Mx128N combine GEMM body (r10 structure: BK=64, double-buffered
// LDS, loads-before-compute, ONE barrier per K-tile). Two operand phases:
// tiles [0,nt0) read (A0,B0), tiles [nt0,ntTot) read (A1,B1) -- same fp32
// accumulator, so combineB computes w1t(*)wi_topnt + t1(*)we_nt in one pass.
// All operands [*][1536] bf16 row-major. C[m][n] = sum_k A[m][k]*Bt[n][k].
// ---------------------------------------------------------------------------
__device__ __forceinline__ void dev_combine_pipe(
        unsigned short* As, unsigned short* Bs,
        const unsigned short* __restrict__ A0,
        const unsigned short* __restrict__ B0,
        const unsigned short* __restrict__ A1,
        const unsigned short* __restrict__ B1,
        unsigned short* __restrict__ C,
        int nt0, int ntTot, int bx, int by) {
    const int m0 = by * 64;
    const int n0 = bx * 128;
    const int t    = threadIdx.x;
    const int lane = t & 63;
    const int w    = t >> 6;
    const int wm   = w >> 1;          // 0..1 : 32-row half
    const int wn   = w & 1;           // 0..1 : 64-col half
    const int lm   = lane & 15;
    const int lq   = lane >> 4;

    const int srow = lane >> 2;       // 0..15
    const int scol = (lane & 3) * 8;  // 0,8,16,24

    // A: [2 panels][64 rows][32] shorts per buffer (4096); 2 chunks/wave.
    size_t ag_off[2];
    int rbA[2];
    #pragma unroll
    for (int i = 0; i < 2; ++i) {
        ag_off[i] = (size_t)(m0 + w * 16 + srow) * 1536 + i * 32 + scol;
        rbA[i]    = i * 2048 + w * 512;
    }
    // B: [2 panels][128 rows][32] shorts per buffer (8192); 4 chunks/wave.
    size_t bg_off[4];
    int rbB[4];
    #pragma unroll
    for (int i = 0; i < 4; ++i) {
        int rows = w * 32 + (i >> 1) * 16;
        bg_off[i] = (size_t)(n0 + rows + srow) * 1536 + (i & 1) * 32 + scol;
        rbB[i]    = (i & 1) * 4096 + rows * 32;
    }

    int aro[2][2], bro[2][4];
    #pragma unroll
    for (int ks = 0; ks < 2; ++ks) {
        #pragma unroll
        for (int mi = 0; mi < 2; ++mi)
            aro[ks][mi] = ks * 2048 + (wm * 32 + mi * 16 + lm) * 32 + lq * 8;
        #pragma unroll
        for (int ni = 0; ni < 4; ++ni)
            bro[ks][ni] = ks * 4096 + (wn * 64 + ni * 16 + lm) * 32 + lq * 8;
    }

    floatx4 acc[2][4] = {};

    auto stage = [&](int s, int nb) {
        const unsigned short* Ab;
        const unsigned short* Bb;
        int kk;
        if (s < nt0) { Ab = A0; Bb = B0; kk = s << 6; }
        else         { Ab = A1; Bb = B1; kk = (s - nt0) << 6; }
        #pragma unroll
        for (int i = 0; i < 2; ++i)
            load_lds16(Ab + ag_off[i] + kk, As + nb * 4096 + rbA[i]);
        #pragma unroll
        for (int i = 0; i < 4; ++i)
            load_lds16(Bb + bg_off[i] + kk, Bs + nb * 8192 + rbB[i]);
    };

    stage(0, 0);
    __syncthreads();

    int buf = 0;
    for (int tt = 0; tt < ntTot; ++tt) {
        if (tt + 1 < ntTot) stage(tt + 1, buf ^ 1);
        const int cA = buf * 4096, cB = buf * 8192;
        #pragma unroll
        for (int ks = 0; ks < 2; ++ks) {
            short8 af[2], bf8[4];
            #pragma unroll
            for (int mi = 0; mi < 2; ++mi)
                af[mi] = *(const short8*)(As + cA + aro[ks][mi]);
            #pragma unroll
            for (int ni = 0; ni < 4; ++ni)
                bf8[ni] = *(const short8*)(Bs + cB + bro[ks][ni]);
            #pragma unroll
            for (int mi = 0; mi < 2; ++mi)
                #pragma unroll
                for (int ni = 0; ni < 4; ++ni)
                    acc[mi][ni] = __builtin_amdgcn_mfma_f32_16x16x32_bf16(
                        af[mi], bf8[ni], acc[mi][ni], 0, 0, 0);
        }
        if (tt + 1 < ntTot) __syncthreads();
        buf ^= 1;
    }

    #pragma unroll
    for (int mi = 0; mi < 2; ++mi) {
        int rbase = m0 + wm * 32 + mi * 16 + lq * 4;
        #pragma unroll
        for (int ni = 0; ni < 4; ++ni) {
            int cc = n0 + wn * 64 + ni * 16 + lm;
            #pragma unroll
            for (int r = 0; r < 4; ++r)
                C[(size_t)(rbase + r) * 1536 + cc] = f2bf(acc[mi][ni][r]);
        }
    }
}

// combineA: t1[n][u] = sum_i w1t[n][i] * wibot_ui[u][i].  Grid 96 blocks.
__global__ __launch_bounds__(256) void combineA_kernel(
        const unsigned short* __restrict__ w1t,
        const unsigned short* __restrict__ wibot_ui,
        unsigned short* __restrict__ t1) {
    __shared__ unsigned short As[2 * 4096];
    __shared__ unsigned short Bs[2 * 8192];
    int b = blockIdx.x;
    dev_combine_pipe(As, Bs, w1t, wibot_ui, w1t, wibot_ui, t1,
                     24, 24, b % 12, b / 12);
}

// b1c[n] = b1[n] + dot(w1t[n,:], gpi_b) + dot(t1[n,:], gpe_b); one wave per n.
__device__ __forceinline__ void dev_bvec2(
        const float* __restrict__ gpi_b, const float* __restrict__ gpe_b,
        const unsigned short* __restrict__ w1t,
        const unsigned short* __restrict__ t1,
        const float* __restrict__ b1, float* __restrict__ b1c, int blk) {
    int n = blk * 4 + (threadIdx.x >> 6);
    int lane = threadIdx.x & 63;
    const unsigned short* r1 = w1t + (size_t)n * 1536;
    const unsigned short* r2 = t1  + (size_t)n * 1536;
    float s = 0.f;
    for (int i = lane; i < 1536; i += 64)
        s += gpi_b[i] * bf2f(r1[i]) + gpe_b[i] * bf2f(r2[i]);
    #pragma unroll
    for (int off = 32; off; off >>= 1) s += __shfl_down(s, off, 64);
    if (lane == 0) b1c[n] = b1[n] + s;
}

// combineB: blocks [0,96) : w1ct = w1t(*)wi_topnt + t1(*)we_nt (K=3072 fused)
//           blocks [96,224): b1c bvec
__global__ __launch_bounds__(256) void combineB_kernel(
        const unsigned short* __restrict__ w1t,
        const unsigned short* __restrict__ wi_topnt,
        const unsigned short* __restrict__ t1,
        const unsigned short* __restrict__ we_nt,
        unsigned short* __restrict__ w1ct,
        const float* __restrict__ gpi_b, const float* __restrict__ gpe_b,
        const float* __restrict__ b1, float* __restrict__ b1c) {
    __shared__ unsigned short As[2 * 4096];
    __shared__ unsigned short Bs[2 * 8192];
    int b = blockIdx.x;
    if (b < 96) {
        dev_combine_pipe(As, Bs, w1t, wi_topnt, t1, we_nt, w1ct,
                         24, 48, b % 12, b / 12);
    } else {
        dev_bvec2(gpi_b, gpe_b, w1t, t1, b1, b1c, b - 96);
    }
}

// ---------------------------------------------------------------------------
// Batch GEMM 1: h1 = relu(x @ W1c^T + b1c), x fp32.  (r10, unchanged)
// 128x128 tile, BK=64, double-buffered LDS, 2-phase pipeline.
// ---------------------------------------------------------------------------
__global__ __launch_bounds__(256) void gemm_a32_kernel(
        const float* __restrict__ A,            // [M][lda] fp32
        const unsigned short* __restrict__ Bt,  // [N][K]  bf16
        const float* __restrict__ bias,         // [N]
        unsigned short* __restrict__ C,         // [M][ldc] bf16
        int K, int lda, int ldc) {
    __shared__ unsigned short As[2 * 8192];     // 32 KB
    __shared__ unsigned short Bs[2 * 8192];     // 32 KB

    const int bid = blockIdx.x;
    const int loc = bid >> 3;                   // 0..63
    const int m0 = ((bid & 7) * 16 + (loc >> 2)) * 128;
    const int n0 = (loc & 3) * 128;

    const int t    = threadIdx.x;
    const int lane = t & 63;
    const int w    = t >> 6;
    const int wm   = w >> 1;
    const int wn   = w & 1;
    const int lm   = lane & 15;
    const int lq   = lane >> 4;

    const int srow = lane >> 2;        // 0..15
    const int scol = (lane & 3) * 8;   // 0,8,16,24

    const float* ag[4];
    const unsigned short* bg[4];
    int rb[4];
    int awr[4];
    #pragma unroll
    for (int i = 0; i < 4; ++i) {
        int rows = w * 32 + (i >> 1) * 16;
        ag[i]  = A  + (size_t)(m0 + rows + srow) * lda + (i & 1) * 32 + scol;
        bg[i]  = Bt + (size_t)(n0 + rows + srow) * K   + (i & 1) * 32 + scol;
        rb[i]  = (i & 1) * 4096 + rows * 32;
        awr[i] = (i & 1) * 4096 + (rows + srow) * 32 + scol;
    }

    int aro[2][4], bro[2][4];
    #pragma unroll
    for (int ks = 0; ks < 2; ++ks)
        #pragma unroll
        for (int i = 0; i < 4; ++i) {
            aro[ks][i] = ks * 4096 + (wm * 64 + i * 16 + lm) * 32 + lq * 8;
            bro[ks][i] = ks * 4096 + (wn * 64 + i * 16 + lm) * 32 + lq * 8;
        }

    floatx4 acc[4][4] = {};
    float4 ra[4][2];

    #pragma unroll
    for (int i = 0; i < 4; ++i) load_lds16(bg[i], Bs + rb[i]);
    #pragma unroll
    for (int i = 0; i < 4; ++i) {
        ra[i][0] = *(const float4*)(ag[i]);
        ra[i][1] = *(const float4*)(ag[i] + 4);
    }
    #pragma unroll
    for (int i = 0; i < 4; ++i)
        *(short8*)(As + awr[i]) = cvt8(ra[i][0], ra[i][1]);
    __syncthreads();

    const int nt = K >> 6;
    int buf = 0;
    for (int tt = 0; tt < nt; ++tt) {
        const int kn = (tt + 1) << 6;
        const int more = kn < K;
        if (more) {
            const int nb = (buf ^ 1) * 8192;
            #pragma unroll
            for (int i = 0; i < 4; ++i)
                load_lds16(bg[i] + kn, Bs + nb + rb[i]);
            #pragma unroll
            for (int i = 0; i < 4; ++i) {
                ra[i][0] = *(const float4*)(ag[i] + kn);
                ra[i][1] = *(const float4*)(ag[i] + kn + 4);
            }
        }
        const int cb = buf * 8192;
        #pragma unroll
        for (int ks = 0; ks < 2; ++ks) {
            short8 af[4], bf8[4];
            #pragma unroll
            for (int i = 0; i < 4; ++i) {
                af[i]  = *(const short8*)(As + cb + aro[ks][i]);
                bf8[i] = *(const short8*)(Bs + cb + bro[ks][i]);
            }
            #pragma unroll
            for (int mi = 0; mi < 4; ++mi)
                #pragma unroll
                for (int ni = 0; ni < 4; ++ni)
                    acc[mi][ni] = __builtin_amdgcn_mfma_f32_16x16x32_bf16(
                        af[mi], bf8[ni], acc[mi][ni], 0, 0, 0);
        }
        if (more) {
            const int nb = (buf ^ 1) * 8192;
            #pragma unroll
            for (int i = 0; i < 4; ++i)
                *(short8*)(As + nb + awr[i]) = cvt8(ra[i][0], ra[i][1]);
            __syncthreads();
        }
        buf ^= 1;
    }

    float bv[4];
    #pragma unroll
    for (int ni = 0; ni < 4; ++ni) bv[ni] = bias[n0 + wn * 64 + ni * 16 + lm];

    #pragma unroll
    for (int mi = 0; mi < 4; ++mi) {
        int rbase = m0 + wm * 64 + mi * 16 + lq * 4;
        #pragma unroll
        for (int ni = 0; ni < 4; ++ni) {
            int cc = n0 + wn * 64 + ni * 16 + lm;
            #pragma unroll
            for (int r = 0; r < 4; ++r) {
                float v = fmaxf(acc[mi][ni][r] + bv[ni], 0.f);
                C[(size_t)(rbase + r) * ldc + cc] = f2bf(v);
            }
        }
    }
}

// ---------------------------------------------------------------------------
// Batch GEMM 2: bf16 A and B via global_load_lds.  (r10, unchanged)
// ---------------------------------------------------------------------------
__global__ __launch_bounds__(256) void gemm_bt_kernel(
        const unsigned short* __restrict__ A,
        const unsigned short* __restrict__ Bt,
        const float* __restrict__ bias,
        unsigned short* __restrict__ C,
        int K, int lda, int ldc) {
    __shared__ unsigned short As[2 * 8192];
    __shared__ unsigned short Bs[2 * 8192];

    const int bid = blockIdx.x;
    const int loc = bid >> 3;
    const int m0 = ((bid & 7) * 16 + (loc >> 2)) * 128;
    const int n0 = (loc & 3) * 128;

    const int t    = threadIdx.x;
    const int lane = t & 63;
    const int w    = t >> 6;
    const int wm   = w >> 1;
    const int wn   = w & 1;
    const int lm   = lane & 15;
    const int lq   = lane >> 4;

    const int srow = lane >> 2;
    const int scol = (lane & 3) * 8;

    const unsigned short* ag[4];
    const unsigned short* bg[4];
    int rb[4];
    #pragma unroll
    for (int i = 0; i < 4; ++i) {
        int rows = w * 32 + (i >> 1) * 16;
        ag[i] = A  + (size_t)(m0 + rows + srow) * lda + (i & 1) * 32 + scol;
        bg[i] = Bt + (size_t)(n0 + rows + srow) * K   + (i & 1) * 32 + scol;
        rb[i] = (i & 1) * 4096 + rows * 32;
    }

    int aro[2][4], bro[2][4];
    #pragma unroll
    for (int ks = 0; ks < 2; ++ks)
        #pragma unroll
        for (int i = 0; i < 4; ++i) {
            aro[ks][i] = ks * 4096 + (wm * 64 + i * 16 + lm) * 32 + lq * 8;
            bro[ks][i] = ks * 4096 + (wn * 64 + i * 16 + lm) * 32 + lq * 8;
        }

    floatx4 acc[4][4] = {};

    #pragma unroll
    for (int i = 0; i < 4; ++i) {
        load_lds16(ag[i], As + rb[i]);
        load_lds16(bg[i], Bs + rb[i]);
    }
    __syncthreads();

    const int nt = K >> 6;
    int buf = 0;
    for (int tt = 0; tt < nt; ++tt) {
        const int kn = (tt + 1) << 6;
        const int more = kn < K;
        if (more) {
            const int nb = (buf ^ 1) * 8192;
            #pragma unroll
            for (int i = 0; i < 4; ++i) {
                load_lds16(ag[i] + kn, As + nb + rb[i]);
                load_lds16(bg[i] + kn, Bs + nb + rb[i]);
            }
        }
        const int cb = buf * 8192;
        #pragma unroll
        for (int ks = 0; ks < 2; ++ks) {
            short8 af[4], bf8[4];
            #pragma unroll
            for (int i = 0; i < 4; ++i) {
                af[i]  = *(const short8*)(As + cb + aro[ks][i]);
                bf8[i] = *(const short8*)(Bs + cb + bro[ks][i]);
            }
            #pragma unroll
            for (int mi = 0; mi < 4; ++mi)
                #pragma unroll
                for (int ni = 0; ni < 4; ++ni)
                    acc[mi][ni] = __builtin_amdgcn_mfma_f32_16x16x32_bf16(
                        af[mi], bf8[ni], acc[mi][ni], 0, 0, 0);
        }
        if (more) __syncthreads();
        buf ^= 1;
    }

    float bv[4];
    #pragma unroll
    for (int ni = 0; ni < 4; ++ni) bv[ni] = bias[n0 + wn * 64 + ni * 16 + lm];

    #pragma unroll
    for (int mi = 0; mi < 4; ++mi) {
        int rbase = m0 + wm * 64 + mi * 16 + lq * 4;
        #pragma unroll
        for (int ni = 0; ni < 4; ++ni) {
            int cc = n0 + wn * 64 + ni * 16 + lm;
            #pragma unroll
            for (int r = 0; r < 4; ++r) {
                float v = fmaxf(acc[mi][ni][r] + bv[ni], 0.f);
                C[(size_t)(rbase + r) * ldc + cc] = f2bf(v);
            }
        }
    }
}

// ---------------------------------------------------------------------------
// head: one wave per row, 16B/lane coalesced, shuffle-reduce 6 sums.
// ---------------------------------------------------------------------------
__global__ void head_kernel(const unsigned short* __restrict__ h,
                            const float* __restrict__ w3,
                            const float* __restrict__ b3,
                            float* __restrict__ out) {
    int row = blockIdx.x * 4 + (threadIdx.x >> 6);
    int lane = threadIdx.x & 63;
    const unsigned short* hp = h + (size_t)row * 512 + lane * 8;
    ushort4 ha = *(const ushort4*)(hp);
    ushort4 hb = *(const ushort4*)(hp + 4);
    float hv[8] = {bf2f(ha.x), bf2f(ha.y), bf2f(ha.z), bf2f(ha.w),
                   bf2f(hb.x), bf2f(hb.y), bf2f(hb.z), bf2f(hb.w)};
    const float* wp = w3 + lane * 48;
    float s[6] = {0.f, 0.f, 0.f, 0.f, 0.f, 0.f};
    #pragma unroll
    for (int j = 0; j < 8; ++j)
        #pragma unroll
        for (int a = 0; a < 6; ++a)
            s[a] += hv[j] * wp[j * 6 + a];
    #pragma unroll
    for (int a = 0; a < 6; ++a)
        #pragma unroll
        for (int off = 32; off; off >>= 1)
            s[a] += __shfl_down(s[a], off, 64);
    if (lane == 0) {
        #pragma unroll
        for (int a = 0; a < 6; ++a)
            out[(size_t)row * 6 + a] = fmaxf(s[a] + b3[a], 0.f);
    }
}

// ---------------------------------------------------------------------------
extern "C" void kernel_launch(void* const* d_in, const int* in_sizes, int n_in,
                              void* d_out, int out_size, void* d_ws, size_t ws_size,
                              hipStream_t stream) {
    const float* x        = (const float*)d_in[0];
    const float* gpe_mask = (const float*)d_in[1];
    const float* gpe_w    = (const float*)d_in[2];
    const float* gpe_b    = (const float*)d_in[3];
    const float* gpi_mask = (const float*)d_in[4];
    const float* gpi_w    = (const float*)d_in[5];
    const float* gpi_b    = (const float*)d_in[6];
    const float* w1       = (const float*)d_in[7];
    const float* b1       = (const float*)d_in[8];
    const float* w2       = (const float*)d_in[9];
    const float* b2       = (const float*)d_in[10];
    const float* w3       = (const float*)d_in[11];
    const float* b3       = (const float*)d_in[12];
    float* out = (float*)d_out;

    // workspace carve (bytes), total ~53 MB
    char* ws = (char*)d_ws;
    unsigned short* h1        = (unsigned short*)(ws);              // B*512
    unsigned short* h2        = (unsigned short*)(ws + 16777216);   // B*512
    unsigned short* wi_topnt  = (unsigned short*)(ws + 33554432);   // [j][i] 1536^2
    unsigned short* wibot_ui  = (unsigned short*)(ws + 38273024);   // [u][i] 1536^2
    unsigned short* we_nt     = (unsigned short*)(ws + 42991616);   // [j][u] 1536^2
    unsigned short* t1        = (unsigned short*)(ws + 47710208);   // [n][u] 512x1536
    unsigned short* w1t       = (unsigned short*)(ws + 49283072);   // [n][i] 512x1536
    unsigned short* w2t       = (unsigned short*)(ws + 50855936);   // [n][k] 512x512
    unsigned short* w1ct      = (unsigned short*)(ws + 51380224);   // [n][j] 512x1536
    float*          b1c       = (float*)(ws + 52953088);            // [512]

    // ---- weight preps ----
    prep_all_kernel<<<dim3(1984), dim3(256), 0, stream>>>(
        gpe_w, gpe_mask, gpi_w, gpi_mask, w1, w2,
        wi_topnt, wibot_ui, we_nt, w1t, w2t);

    // ---- combineA: t1 = w1t (*) wibot_ui ----
    combineA_kernel<<<dim3(96), dim3(256), 0, stream>>>(w1t, wibot_ui, t1);

    // ---- combineB: w1ct = w1t(*)wi_topnt + t1(*)we_nt ; b1c ----
    combineB_kernel<<<dim3(224), dim3(256), 0, stream>>>(
        w1t, wi_topnt, t1, we_nt, w1ct, gpi_b, gpe_b, b1, b1c);

    // ---- batch chain ----
    gemm_a32_kernel<<<dim3(512), dim3(256), 0, stream>>>(
        x, w1ct, b1c, h1, 1536, 1536, 512);
    gemm_bt_kernel<<<dim3(512), dim3(256), 0, stream>>>(
        h1, w2t, b2, h2, 512, 512, 512);
    head_kernel<<<dim3(16384 / 4), dim3(256), 0, stream>>>(h2, w3, b3, out);
}

// Round 4
// 322.429 us; speedup vs baseline: 1.0741x; 1.0741x over previous
//
#include <hip/hip_runtime.h>
#include <stdint.h>

// ---------------------------------------------------------------------------
// CTBG circuit, round 12.
//   r11 post-mortem: combine chain (96-block grids, 24/48 serial K-iters) is
//   ~100us -- grid-starved AND serial-K. Fix: split-K with f32 atomics.
//     combineA: 3 K-chunks x 96 tiles = 288 blocks, 8 iters  -> t1f (f32)
//     combineB: 6 chunks (2 phases x 3) = 576 blocks, 8 iters -> w1cf (f32)
//     finalize: w1cf -> w1ct bf16 + b1c bias fold
//   t1f/w1cf alias h2's region (dead until gemm_bt). Zeroing in prep_all.
//   gemm_a32 / gemm_bt / head byte-identical to r10.
// ---------------------------------------------------------------------------

typedef __attribute__((ext_vector_type(8))) short short8;
typedef __attribute__((ext_vector_type(4))) float floatx4;

typedef const __attribute__((address_space(1))) void* gas1_cvp;
typedef __attribute__((address_space(3))) void* gas3_vp;

__device__ __forceinline__ void load_lds16(const void* g, void* s) {
    __builtin_amdgcn_global_load_lds((gas1_cvp)g, (gas3_vp)s, 16, 0, 0);
}

__device__ __forceinline__ unsigned short f2bf(float f) {
    unsigned int u = __float_as_uint(f);
    u = u + 0x7fffu + ((u >> 16) & 1u);          // RNE
    return (unsigned short)(u >> 16);
}
__device__ __forceinline__ float bf2f(unsigned short h) {
    return __uint_as_float(((unsigned int)h) << 16);
}
__device__ __forceinline__ short8 cvt8(float4 a, float4 b) {
    short8 r;
    r[0] = (short)f2bf(a.x); r[1] = (short)f2bf(a.y);
    r[2] = (short)f2bf(a.z); r[3] = (short)f2bf(a.w);
    r[4] = (short)f2bf(b.x); r[5] = (short)f2bf(b.y);
    r[6] = (short)f2bf(b.z); r[7] = (short)f2bf(b.w);
    return r;
}

// ---------------------------------------------------------------------------
// Prep bodies. Block = 256 threads.
// ---------------------------------------------------------------------------
__device__ __forceinline__ void dev_prep_t(
        float (*tile)[65],
        const float* __restrict__ w, const float* __restrict__ mask,
        unsigned short* __restrict__ out,
        int ldw, int ldm, int ldo, int bx, int by) {
    int n0 = bx * 64;
    int k0 = by * 64;
    int t = threadIdx.x;
    int c4 = (t & 15) * 4;
    int r  = t >> 4;

    #pragma unroll
    for (int p = 0; p < 4; ++p) {
        int kk = r + p * 16;
        float4 v = *(const float4*)(w + (size_t)(k0 + kk) * ldw + n0 + c4);
        tile[c4 + 0][kk] = v.x;
        tile[c4 + 1][kk] = v.y;
        tile[c4 + 2][kk] = v.z;
        tile[c4 + 3][kk] = v.w;
    }
    __syncthreads();
    #pragma unroll
    for (int p = 0; p < 4; ++p) {
        int nn = r + p * 16;
        float mx = 1.f, my = 1.f, mz = 1.f, mw = 1.f;
        if (mask) {
            float4 m = *(const float4*)(mask + (size_t)(n0 + nn) * ldm + k0 + c4);
            mx = m.x; my = m.y; mz = m.z; mw = m.w;
        }
        ushort4 o;
        o.x = f2bf(tile[nn][c4 + 0] * mx);
        o.y = f2bf(tile[nn][c4 + 1] * my);
        o.z = f2bf(tile[nn][c4 + 2] * mz);
        o.w = f2bf(tile[nn][c4 + 3] * mw);
        *(ushort4*)(out + (size_t)(n0 + nn) * ldo + k0 + c4) = o;
    }
}

// Non-transposing: out[r][c] = bf16( w[r][c] * mask[c][r] )
__device__ __forceinline__ void dev_prep_nt(
        float (*tile)[65],
        const float* __restrict__ w, const float* __restrict__ mask,
        unsigned short* __restrict__ out,
        int ldw, int ldm, int ldo, int bx, int by) {
    int j0 = bx * 64;
    int i0 = by * 64;
    int t = threadIdx.x;
    int c4 = (t & 15) * 4;
    int r  = t >> 4;

    #pragma unroll
    for (int p = 0; p < 4; ++p) {
        int jj = r + p * 16;
        float4 m = *(const float4*)(mask + (size_t)(j0 + jj) * ldm + i0 + c4);
        tile[c4 + 0][jj] = m.x;
        tile[c4 + 1][jj] = m.y;
        tile[c4 + 2][jj] = m.z;
        tile[c4 + 3][jj] = m.w;
    }
    __syncthreads();
    #pragma unroll
    for (int p = 0; p < 4; ++p) {
        int ii = r + p * 16;
        float4 v = *(const float4*)(w + (size_t)(i0 + ii) * ldw + j0 + c4);
        ushort4 o;
        o.x = f2bf(v.x * tile[ii][c4 + 0]);
        o.y = f2bf(v.y * tile[ii][c4 + 1]);
        o.z = f2bf(v.z * tile[ii][c4 + 2]);
        o.w = f2bf(v.w * tile[ii][c4 + 3]);
        *(ushort4*)(out + (size_t)(i0 + ii) * ldo + j0 + c4) = o;
    }
}

// All 5 weight preps + zeroing of the 6 MB f32 accumulator region.
// blocks [0,1984): preps as r11; [1984,2368): zero t1f+w1cf (16 KB/block).
__global__ __launch_bounds__(256) void prep_all_kernel(
        const float* __restrict__ gpe_w, const float* __restrict__ gpe_mask,
        const float* __restrict__ gpi_w, const float* __restrict__ gpi_mask,
        const float* __restrict__ w1, const float* __restrict__ w2,
        unsigned short* __restrict__ wi_topnt, unsigned short* __restrict__ wibot_ui,
        unsigned short* __restrict__ we_nt, unsigned short* __restrict__ w1t,
        unsigned short* __restrict__ w2t, float* __restrict__ zero_base) {
    __shared__ float tile[64][65];
    int b = blockIdx.x;
    if (b < 576) {
        dev_prep_nt(tile, gpi_w, gpi_mask, wi_topnt, 1536, 3072, 1536,
                    b % 24, b / 24);
    } else if (b < 1152) {
        int lb = b - 576;
        dev_prep_nt(tile, gpi_w + (size_t)1536 * 1536, gpi_mask + 1536, wibot_ui,
                    1536, 3072, 1536, lb % 24, lb / 24);
    } else if (b < 1728) {
        int lb = b - 1152;
        dev_prep_nt(tile, gpe_w, gpe_mask, we_nt, 1536, 1536, 1536,
                    lb % 24, lb / 24);
    } else if (b < 1920) {
        int lb = b - 1728;
        dev_prep_t(tile, w1, nullptr, w1t, 512, 0, 1536, lb % 8, lb / 8);
    } else if (b < 1984) {
        int lb = b - 1920;
        dev_prep_t(tile, w2, nullptr, w2t, 512, 0, 512, lb % 8, lb / 8);
    } else {
        // zero 6291456 B = 384 blocks * 256 thr * 64 B
        float4 z = {0.f, 0.f, 0.f, 0.f};
        float* p = zero_base + (size_t)(b - 1984) * 4096 + threadIdx.x * 16;
        #pragma unroll
        for (int i = 0; i < 4; ++i) *(float4*)(p + i * 4) = z;
    }
}

// ---------------------------------------------------------------------------
// Split-K combine GEMM body: 64Mx128N tile, BK=64, dbuf LDS, pipelined
// (loads-before-compute, ONE barrier/iter). ntl K-tiles starting at element
// kbase. Epilogue: f32 atomicAdd into C. A operand bf16 (global_load_lds) or
// f32 (reg-stage + cvt + ds_write, gemm_a32 pattern) per template flag.
// All operands row-major ld=1536. C[m][n] += sum_k A[m][k]*B[n][k].
// ---------------------------------------------------------------------------
template <bool F32A>
__device__ __forceinline__ void dev_combine_splitk(
        unsigned short* As, unsigned short* Bs,
        const void* __restrict__ Aop,
        const unsigned short* __restrict__ B,
        float* __restrict__ C,
        int kbase, int ntl, int bx, int by) {
    const int m0 = by * 64;
    const int n0 = bx * 128;
    const int t    = threadIdx.x;
    const int lane = t & 63;
    const int w    = t >> 6;
    const int wm   = w >> 1;          // 32-row half
    const int wn   = w & 1;           // 64-col half
    const int lm   = lane & 15;
    const int lq   = lane >> 4;

    const int srow = lane >> 2;       // 0..15
    const int scol = (lane & 3) * 8;  // 0,8,16,24

    // A: [2 k-panels][64 rows][32] per buffer (4096 shorts); 2 chunks/wave
    size_t aidx[2];
    int rbA[2], awr[2];
    #pragma unroll
    for (int i = 0; i < 2; ++i) {
        aidx[i] = (size_t)(m0 + w * 16 + srow) * 1536 + i * 32 + scol + kbase;
        rbA[i]  = i * 2048 + w * 512;
        awr[i]  = i * 2048 + (w * 16 + srow) * 32 + scol;
    }
    // B: [2 k-panels][128 rows][32] per buffer (8192 shorts); 4 chunks/wave
    size_t bidx[4];
    int rbB[4];
    #pragma unroll
    for (int i = 0; i < 4; ++i) {
        int rows = w * 32 + (i >> 1) * 16;
        bidx[i] = (size_t)(n0 + rows + srow) * 1536 + (i & 1) * 32 + scol + kbase;
        rbB[i]  = (i & 1) * 4096 + rows * 32;
    }

    int aro[2][2], bro[2][4];
    #pragma unroll
    for (int ks = 0; ks < 2; ++ks) {
        #pragma unroll
        for (int mi = 0; mi < 2; ++mi)
            aro[ks][mi] = ks * 2048 + (wm * 32 + mi * 16 + lm) * 32 + lq * 8;
        #pragma unroll
        for (int ni = 0; ni < 4; ++ni)
            bro[ks][ni] = ks * 4096 + (wn * 64 + ni * 16 + lm) * 32 + lq * 8;
    }

    const float* Af = (const float*)Aop;
    const unsigned short* Ab = (const unsigned short*)Aop;

    floatx4 acc[2][4] = {};
    float4 ra[2][2];

    // ---- prologue: stage K-tile 0 into buffer 0 ----
    #pragma unroll
    for (int i = 0; i < 4; ++i) load_lds16(B + bidx[i], Bs + rbB[i]);
    if (F32A) {
        #pragma unroll
        for (int i = 0; i < 2; ++i) {
            ra[i][0] = *(const float4*)(Af + aidx[i]);
            ra[i][1] = *(const float4*)(Af + aidx[i] + 4);
        }
        #pragma unroll
        for (int i = 0; i < 2; ++i)
            *(short8*)(As + awr[i]) = cvt8(ra[i][0], ra[i][1]);
    } else {
        #pragma unroll
        for (int i = 0; i < 2; ++i) load_lds16(Ab + aidx[i], As + rbA[i]);
    }
    __syncthreads();

    int buf = 0;
    for (int tt = 0; tt < ntl; ++tt) {
        const int kn = (tt + 1) << 6;
        const int more = tt + 1 < ntl;
        if (more) {
            const int nbA = (buf ^ 1) * 4096;
            const int nbB = (buf ^ 1) * 8192;
            #pragma unroll
            for (int i = 0; i < 4; ++i)
                load_lds16(B + bidx[i] + kn, Bs + nbB + rbB[i]);
            if (F32A) {
                #pragma unroll
                for (int i = 0; i < 2; ++i) {
                    ra[i][0] = *(const float4*)(Af + aidx[i] + kn);
                    ra[i][1] = *(const float4*)(Af + aidx[i] + kn + 4);
                }
            } else {
                #pragma unroll
                for (int i = 0; i < 2; ++i)
                    load_lds16(Ab + aidx[i] + kn, As + nbA + rbA[i]);
            }
        }
        const int cA = buf * 4096, cB = buf * 8192;
        #pragma unroll
        for (int ks = 0; ks < 2; ++ks) {
            short8 af[2], bf8[4];
            #pragma unroll
            for (int mi = 0; mi < 2; ++mi)
                af[mi] = *(const short8*)(As + cA + aro[ks][mi]);
            #pragma unroll
            for (int ni = 0; ni < 4; ++ni)
                bf8[ni] = *(const short8*)(Bs + cB + bro[ks][ni]);
            #pragma unroll
            for (int mi = 0; mi < 2; ++mi)
                #pragma unroll
                for (int ni = 0; ni < 4; ++ni)
                    acc[mi][ni] = __builtin_amdgcn_mfma_f32_16x16x32_bf16(
                        af[mi], bf8[ni], acc[mi][ni], 0, 0, 0);
        }
        if (more) {
            if (F32A) {
                const int nbA = (buf ^ 1) * 4096;
                #pragma unroll
                for (int i = 0; i < 2; ++i)
                    *(short8*)(As + nbA + awr[i]) = cvt8(ra[i][0], ra[i][1]);
            }
            __syncthreads();
        }
        buf ^= 1;
    }

    #pragma unroll
    for (int mi = 0; mi < 2; ++mi) {
        int rbase = m0 + wm * 32 + mi * 16 + lq * 4;
        #pragma unroll
        for (int ni = 0; ni < 4; ++ni) {
            int cc = n0 + wn * 64 + ni * 16 + lm;
            #pragma unroll
            for (int r = 0; r < 4; ++r)
                unsafeAtomicAdd(&C[(size_t)(rbase + r) * 1536 + cc],
                                acc[mi][ni][r]);
        }
    }
}

// combineA: t1f[n][u] += sum_i w1t[n][i]*wibot_ui[u][i].
// Grid 288 = 3 K-chunks x (12 bx x 8 by); 8 K-tiles per chunk.
__global__ __launch_bounds__(256) void combineA_kernel(
        const unsigned short* __restrict__ w1t,
        const unsigned short* __restrict__ wibot_ui,
        float* __restrict__ t1f) {
    __shared__ unsigned short As[2 * 4096];
    __shared__ unsigned short Bs[2 * 8192];
    int b = blockIdx.x;
    int s = b / 96;                 // K-chunk 0..2
    int r = b % 96;
    dev_combine_splitk<false>(As, Bs, w1t, wibot_ui, t1f,
                              s * 512, 8, r % 12, r / 12);
}

// combineB: w1cf[n][j] += w1t(*)wi_topnt + t1f(*)we_nt, split-K.
// Grid 576 = 6 chunks x 96; chunks 0-2 phase0 (bf16 A), 3-5 phase1 (f32 A).
__global__ __launch_bounds__(256) void combineB_kernel(
        const unsigned short* __restrict__ w1t,
        const unsigned short* __restrict__ wi_topnt,
        const float* __restrict__ t1f,
        const unsigned short* __restrict__ we_nt,
        float* __restrict__ w1cf) {
    __shared__ unsigned short As[2 * 4096];
    __shared__ unsigned short Bs[2 * 8192];
    int b = blockIdx.x;
    int c = b / 96;                 // chunk 0..5
    int r = b % 96;
    int kbase = (c % 3) * 512;
    if (c < 3) {
        dev_combine_splitk<false>(As, Bs, w1t, wi_topnt, w1cf,
                                  kbase, 8, r % 12, r / 12);
    } else {
        dev_combine_splitk<true>(As, Bs, t1f, we_nt, w1cf,
                                 kbase, 8, r % 12, r / 12);
    }
}

// finalize: blocks [0,384): w1ct = bf16(w1cf), 2048 elems/block;
//           blocks [384,512): b1c[n] = b1[n] + w1t[n,:].gpi_b + t1f[n,:].gpe_b
__global__ __launch_bounds__(256) void finalize_kernel(
        const float* __restrict__ w1cf, unsigned short* __restrict__ w1ct,
        const unsigned short* __restrict__ w1t, const float* __restrict__ t1f,
        const float* __restrict__ gpi_b, const float* __restrict__ gpe_b,
        const float* __restrict__ b1, float* __restrict__ b1c) {
    int b = blockIdx.x;
    if (b < 384) {
        size_t base = (size_t)b * 2048 + threadIdx.x * 8;
        float4 v0 = *(const float4*)(w1cf + base);
        float4 v1 = *(const float4*)(w1cf + base + 4);
        ushort4 o0, o1;
        o0.x = f2bf(v0.x); o0.y = f2bf(v0.y); o0.z = f2bf(v0.z); o0.w = f2bf(v0.w);
        o1.x = f2bf(v1.x); o1.y = f2bf(v1.y); o1.z = f2bf(v1.z); o1.w = f2bf(v1.w);
        *(ushort4*)(w1ct + base) = o0;
        *(ushort4*)(w1ct + base + 4) = o1;
    } else {
        int n = (b - 384) * 4 + (threadIdx.x >> 6);
        int lane = threadIdx.x & 63;
        const unsigned short* r1 = w1t + (size_t)n * 1536;
        const float* r2 = t1f + (size_t)n * 1536;
        float s = 0.f;
        for (int i = lane; i < 1536; i += 64)
            s += gpi_b[i] * bf2f(r1[i]) + gpe_b[i] * r2[i];
        #pragma unroll
        for (int off = 32; off; off >>= 1) s += __shfl_down(s, off, 64);
        if (lane == 0) b1c[n] = b1[n] + s;
    }
}

// ---------------------------------------------------------------------------
// Batch GEMM 1: h1 = relu(x @ W1c^T + b1c), x fp32.  (r10, unchanged)
// ---------------------------------------------------------------------------
__global__ __launch_bounds__(256) void gemm_a32_kernel(
        const float* __restrict__ A,            // [M][lda] fp32
        const unsigned short* __restrict__ Bt,  // [N][K]  bf16
        const float* __restrict__ bias,         // [N]
        unsigned short* __restrict__ C,         // [M][ldc] bf16
        int K, int lda, int ldc) {
    __shared__ unsigned short As[2 * 8192];     // 32 KB
    __shared__ unsigned short Bs[2 * 8192];     // 32 KB

    const int bid = blockIdx.x;
    const int loc = bid >> 3;                   // 0..63
    const int m0 = ((bid & 7) * 16 + (loc >> 2)) * 128;
    const int n0 = (loc & 3) * 128;

    const int t    = threadIdx.x;
    const int lane = t & 63;
    const int w    = t >> 6;
    const int wm   = w >> 1;
    const int wn   = w & 1;
    const int lm   = lane & 15;
    const int lq   = lane >> 4;

    const int srow = lane >> 2;        // 0..15
    const int scol = (lane & 3) * 8;   // 0,8,16,24

    const float* ag[4];
    const unsigned short* bg[4];
    int rb[4];
    int awr[4];
    #pragma unroll
    for (int i = 0; i < 4; ++i) {
        int rows = w * 32 + (i >> 1) * 16;
        ag[i]  = A  + (size_t)(m0 + rows + srow) * lda + (i & 1) * 32 + scol;
        bg[i]  = Bt + (size_t)(n0 + rows + srow) * K   + (i & 1) * 32 + scol;
        rb[i]  = (i & 1) * 4096 + rows * 32;
        awr[i] = (i & 1) * 4096 + (rows + srow) * 32 + scol;
    }

    int aro[2][4], bro[2][4];
    #pragma unroll
    for (int ks = 0; ks < 2; ++ks)
        #pragma unroll
        for (int i = 0; i < 4; ++i) {
            aro[ks][i] = ks * 4096 + (wm * 64 + i * 16 + lm) * 32 + lq * 8;
            bro[ks][i] = ks * 4096 + (wn * 64 + i * 16 + lm) * 32 + lq * 8;
        }

    floatx4 acc[4][4] = {};
    float4 ra[4][2];

    #pragma unroll
    for (int i = 0; i < 4; ++i) load_lds16(bg[i], Bs + rb[i]);
    #pragma unroll
    for (int i = 0; i < 4; ++i) {
        ra[i][0] = *(const float4*)(ag[i]);
        ra[i][1] = *(const float4*)(ag[i] + 4);
    }
    #pragma unroll
    for (int i = 0; i < 4; ++i)
        *(short8*)(As + awr[i]) = cvt8(ra[i][0], ra[i][1]);
    __syncthreads();

    const int nt = K >> 6;
    int buf = 0;
    for (int tt = 0; tt < nt; ++tt) {
        const int kn = (tt + 1) << 6;
        const int more = kn < K;
        if (more) {
            const int nb = (buf ^ 1) * 8192;
            #pragma unroll
            for (int i = 0; i < 4; ++i)
                load_lds16(bg[i] + kn, Bs + nb + rb[i]);
            #pragma unroll
            for (int i = 0; i < 4; ++i) {
                ra[i][0] = *(const float4*)(ag[i] + kn);
                ra[i][1] = *(const float4*)(ag[i] + kn + 4);
            }
        }
        const int cb = buf * 8192;
        #pragma unroll
        for (int ks = 0; ks < 2; ++ks) {
            short8 af[4], bf8[4];
            #pragma unroll
            for (int i = 0; i < 4; ++i) {
                af[i]  = *(const short8*)(As + cb + aro[ks][i]);
                bf8[i] = *(const short8*)(Bs + cb + bro[ks][i]);
            }
            #pragma unroll
            for (int mi = 0; mi < 4; ++mi)
                #pragma unroll
                for (int ni = 0; ni < 4; ++ni)
                    acc[mi][ni] = __builtin_amdgcn_mfma_f32_16x16x32_bf16(
                        af[mi], bf8[ni], acc[mi][ni], 0, 0, 0);
        }
        if (more) {
            const int nb = (buf ^ 1) * 8192;
            #pragma unroll
            for (int i = 0; i < 4; ++i)
                *(short8*)(As + nb + awr[i]) = cvt8(ra[i][0], ra[i][1]);
            __syncthreads();
        }
        buf ^= 1;
    }

    float bv[4];
    #pragma unroll
    for (int ni = 0; ni < 4; ++ni) bv[ni] = bias[n0 + wn * 64 + ni * 16 + lm];

    #pragma unroll
    for (int mi = 0; mi < 4; ++mi) {
        int rbase = m0 + wm * 64 + mi * 16 + lq * 4;
        #pragma unroll
        for (int ni = 0; ni < 4; ++ni) {
            int cc = n0 + wn * 64 + ni * 16 + lm;
            #pragma unroll
            for (int r = 0; r < 4; ++r) {
                float v = fmaxf(acc[mi][ni][r] + bv[ni], 0.f);
                C[(size_t)(rbase + r) * ldc + cc] = f2bf(v);
            }
        }
    }
}

// ---------------------------------------------------------------------------
// Batch GEMM 2: bf16 A and B via global_load_lds.  (r10, unchanged)
// ---------------------------------------------------------------------------
__global__ __launch_bounds__(256) void gemm_bt_kernel(
        const unsigned short* __restrict__ A,
        const unsigned short* __restrict__ Bt,
        const float* __restrict__ bias,
        unsigned short* __restrict__ C,
        int K, int lda, int ldc) {
    __shared__ unsigned short As[2 * 8192];
    __shared__ unsigned short Bs[2 * 8192];

    const int bid = blockIdx.x;
    const int loc = bid >> 3;
    const int m0 = ((bid & 7) * 16 + (loc >> 2)) * 128;
    const int n0 = (loc & 3) * 128;

    const int t    = threadIdx.x;
    const int lane = t & 63;
    const int w    = t >> 6;
    const int wm   = w >> 1;
    const int wn   = w & 1;
    const int lm   = lane & 15;
    const int lq   = lane >> 4;

    const int srow = lane >> 2;
    const int scol = (lane & 3) * 8;

    const unsigned short* ag[4];
    const unsigned short* bg[4];
    int rb[4];
    #pragma unroll
    for (int i = 0; i < 4; ++i) {
        int rows = w * 32 + (i >> 1) * 16;
        ag[i] = A  + (size_t)(m0 + rows + srow) * lda + (i & 1) * 32 + scol;
        bg[i] = Bt + (size_t)(n0 + rows + srow) * K   + (i & 1) * 32 + scol;
        rb[i] = (i & 1) * 4096 + rows * 32;
    }

    int aro[2][4], bro[2][4];
    #pragma unroll
    for (int ks = 0; ks < 2; ++ks)
        #pragma unroll
        for (int i = 0; i < 4; ++i) {
            aro[ks][i] = ks * 4096 + (wm * 64 + i * 16 + lm) * 32 + lq * 8;
            bro[ks][i] = ks * 4096 + (wn * 64 + i * 16 + lm) * 32 + lq * 8;
        }

    floatx4 acc[4][4] = {};

    #pragma unroll
    for (int i = 0; i < 4; ++i) {
        load_lds16(ag[i], As + rb[i]);
        load_lds16(bg[i], Bs + rb[i]);
    }
    __syncthreads();

    const int nt = K >> 6;
    int buf = 0;
    for (int tt = 0; tt < nt; ++tt) {
        const int kn = (tt + 1) << 6;
        const int more = kn < K;
        if (more) {
            const int nb = (buf ^ 1) * 8192;
            #pragma unroll
            for (int i = 0; i < 4; ++i) {
                load_lds16(ag[i] + kn, As + nb + rb[i]);
                load_lds16(bg[i] + kn, Bs + nb + rb[i]);
            }
        }
        const int cb = buf * 8192;
        #pragma unroll
        for (int ks = 0; ks < 2; ++ks) {
            short8 af[4], bf8[4];
            #pragma unroll
            for (int i = 0; i < 4; ++i) {
                af[i]  = *(const short8*)(As + cb + aro[ks][i]);
                bf8[i] = *(const short8*)(Bs + cb + bro[ks][i]);
            }
            #pragma unroll
            for (int mi = 0; mi < 4; ++mi)
                #pragma unroll
                for (int ni = 0; ni < 4; ++ni)
                    acc[mi][ni] = __builtin_amdgcn_mfma_f32_16x16x32_bf16(
                        af[mi], bf8[ni], acc[mi][ni], 0, 0, 0);
        }
        if (more) __syncthreads();
        buf ^= 1;
    }

    float bv[4];
    #pragma unroll
    for (int ni = 0; ni < 4; ++ni) bv[ni] = bias[n0 + wn * 64 + ni * 16 + lm];

    #pragma unroll
    for (int mi = 0; mi < 4; ++mi) {
        int rbase = m0 + wm * 64 + mi * 16 + lq * 4;
        #pragma unroll
        for (int ni = 0; ni < 4; ++ni) {
            int cc = n0 + wn * 64 + ni * 16 + lm;
            #pragma unroll
            for (int r = 0; r < 4; ++r) {
                float v = fmaxf(acc[mi][ni][r] + bv[ni], 0.f);
                C[(size_t)(rbase + r) * ldc + cc] = f2bf(v);
            }
        }
    }
}

// ---------------------------------------------------------------------------
// head: one wave per row, 16B/lane coalesced, shuffle-reduce 6 sums.
// ---------------------------------------------------------------------------
__global__ void head_kernel(const unsigned short* __restrict__ h,
                            const float* __restrict__ w3,
                            const float* __restrict__ b3,
                            float* __restrict__ out) {
    int row = blockIdx.x * 4 + (threadIdx.x >> 6);
    int lane = threadIdx.x & 63;
    const unsigned short* hp = h + (size_t)row * 512 + lane * 8;
    ushort4 ha = *(const ushort4*)(hp);
    ushort4 hb = *(const ushort4*)(hp + 4);
    float hv[8] = {bf2f(ha.x), bf2f(ha.y), bf2f(ha.z), bf2f(ha.w),
                   bf2f(hb.x), bf2f(hb.y), bf2f(hb.z), bf2f(hb.w)};
    const float* wp = w3 + lane * 48;
    float s[6] = {0.f, 0.f, 0.f, 0.f, 0.f, 0.f};
    #pragma unroll
    for (int j = 0; j < 8; ++j)
        #pragma unroll
        for (int a = 0; a < 6; ++a)
            s[a] += hv[j] * wp[j * 6 + a];
    #pragma unroll
    for (int a = 0; a < 6; ++a)
        #pragma unroll
        for (int off = 32; off; off >>= 1)
            s[a] += __shfl_down(s[a], off, 64);
    if (lane == 0) {
        #pragma unroll
        for (int a = 0; a < 6; ++a)
            out[(size_t)row * 6 + a] = fmaxf(s[a] + b3[a], 0.f);
    }
}

// ---------------------------------------------------------------------------
extern "C" void kernel_launch(void* const* d_in, const int* in_sizes, int n_in,
                              void* d_out, int out_size, void* d_ws, size_t ws_size,
                              hipStream_t stream) {
    const float* x        = (const float*)d_in[0];
    const float* gpe_mask = (const float*)d_in[1];
    const float* gpe_w    = (const float*)d_in[2];
    const float* gpe_b    = (const float*)d_in[3];
    const float* gpi_mask = (const float*)d_in[4];
    const float* gpi_w    = (const float*)d_in[5];
    const float* gpi_b    = (const float*)d_in[6];
    const float* w1       = (const float*)d_in[7];
    const float* b1       = (const float*)d_in[8];
    const float* w2       = (const float*)d_in[9];
    const float* b2       = (const float*)d_in[10];
    const float* w3       = (const float*)d_in[11];
    const float* b3       = (const float*)d_in[12];
    float* out = (float*)d_out;

    // workspace carve (bytes), total ~51.4 MB.
    // t1f/w1cf ALIAS h2's region: h2 is only written by gemm_bt, which runs
    // after finalize has consumed t1f/w1cf.
    char* ws = (char*)d_ws;
    unsigned short* h1        = (unsigned short*)(ws);              // B*512 bf16
    unsigned short* h2        = (unsigned short*)(ws + 16777216);   // B*512 bf16
    float*          t1f       = (float*)(ws + 16777216);            // 512x1536 f32
    float*          w1cf      = (float*)(ws + 19922944);            // 512x1536 f32
    unsigned short* wi_topnt  = (unsigned short*)(ws + 33554432);   // [j][i] 1536^2
    unsigned short* wibot_ui  = (unsigned short*)(ws + 38273024);   // [u][i] 1536^2
    unsigned short* we_nt     = (unsigned short*)(ws + 42991616);   // [j][u] 1536^2
    unsigned short* w1t       = (unsigned short*)(ws + 47710208);   // [n][i] 512x1536
    unsigned short* w2t       = (unsigned short*)(ws + 49283072);   // [n][k] 512x512
    unsigned short* w1ct      = (unsigned short*)(ws + 49807360);   // [n][j] 512x1536
    float*          b1c       = (float*)(ws + 51380224);            // [512]

    // ---- weight preps + zero the f32 accumulators (t1f,w1cf adjacent) ----
    prep_all_kernel<<<dim3(2368), dim3(256), 0, stream>>>(
        gpe_w, gpe_mask, gpi_w, gpi_mask, w1, w2,
        wi_topnt, wibot_ui, we_nt, w1t, w2t, t1f);

    // ---- combineA: t1f = w1t (*) wibot_ui  (split-K=3) ----
    combineA_kernel<<<dim3(288), dim3(256), 0, stream>>>(w1t, wibot_ui, t1f);

    // ---- combineB: w1cf = w1t(*)wi_topnt + t1f(*)we_nt  (split-K 6) ----
    combineB_kernel<<<dim3(576), dim3(256), 0, stream>>>(
        w1t, wi_topnt, t1f, we_nt, w1cf);

    // ---- finalize: w1ct bf16 + b1c ----
    finalize_kernel<<<dim3(512), dim3(256), 0, stream>>>(
        w1cf, w1ct, w1t, t1f, gpi_b, gpe_b, b1, b1c);

    // ---- batch chain (r10, unchanged) ----
    gemm_a32_kernel<<<dim3(512), dim3(256), 0, stream>>>(
        x, w1ct, b1c, h1, 1536, 1536, 512);
    gemm_bt_kernel<<<dim3(512), dim3(256), 0, stream>>>(
        h1, w2t, b2, h2, 512, 512, 512);
    head_kernel<<<dim3(16384 / 4), dim3(256), 0, stream>>>(h2, w3, b3, out);
}